// Round 4
// baseline (8377.884 us; speedup 1.0000x reference)
//
#include <hip/hip_runtime.h>
#include <cstddef>

#define NB 32
#define NT 512
#define ND 1024
#define NH 1024
#define NG 4096  // 4*NH
#define NBLK 64  // persistent blocks

typedef unsigned short ushortT;
typedef __attribute__((ext_vector_type(8))) short short8;   // 8 bf16 = 4 VGPR
typedef __attribute__((ext_vector_type(4))) float f32x4;

__device__ __forceinline__ ushortT f2bf(float f) {
    union { float f; unsigned u; } v; v.f = f;
    unsigned r = v.u + 0x7FFFu + ((v.u >> 16) & 1u);   // RNE
    return (ushortT)(r >> 16);
}

__device__ __forceinline__ float pick4(float a0, float a1, float a2, float a3, int s) {
    float lo = (s & 1) ? a1 : a0;
    float hi = (s & 1) ? a3 : a2;
    return (s & 2) ? hi : lo;
}

// ---------------------------------------------------------------------------
// cast float -> bf16, 4 elems/thread
// ---------------------------------------------------------------------------
__global__ __launch_bounds__(256) void cast_bf16(const float* __restrict__ src,
                                                 ushortT* __restrict__ dst, int n4)
{
    int i = blockIdx.x * 256 + threadIdx.x;
    if (i < n4) {
        float4 v = ((const float4*)src)[i];
        ushort4 o;
        o.x = f2bf(v.x); o.y = f2bf(v.y); o.z = f2bf(v.z); o.w = f2bf(v.w);
        ((ushort4*)dst)[i] = o;
    }
}

// ---------------------------------------------------------------------------
// transpose + cast: src f32 [1024][4096] -> dst bf16 [4096][1024]
// permute=1 remaps dst row n=(g*1024+j) -> (j>>2)*16 + g*4 + (j&3)
// ---------------------------------------------------------------------------
__global__ __launch_bounds__(256) void transpose_cast(
    const float* __restrict__ src, ushortT* __restrict__ dst, int permute)
{
    __shared__ ushortT tile[64][66];
    const int c0 = blockIdx.x * 64, r0 = blockIdx.y * 64;
    const int cc = threadIdx.x & 63, rq = threadIdx.x >> 6;
    #pragma unroll
    for (int ps = 0; ps < 16; ++ps) {
        int r = ps * 4 + rq;
        tile[cc][r] = f2bf(src[(size_t)(r0 + r) * NG + c0 + cc]);
    }
    __syncthreads();
    #pragma unroll
    for (int ps = 0; ps < 16; ++ps) {
        int cl = ps * 4 + rq;
        int n  = c0 + cl;
        int drow = permute ? ((((n & 1023) >> 2) << 4) | ((n >> 10) << 2) | (n & 3))
                           : n;
        dst[(size_t)drow * 1024 + r0 + cc] = tile[cl][cc];
    }
}

// ---------------------------------------------------------------------------
// xW GEMM, bf16 MFMA (unchanged from round 3)
// ---------------------------------------------------------------------------
__global__ __launch_bounds__(256) void gemm_xw_mfma(
    const ushortT* __restrict__ xb,   // [NB*NT][ND] bf16
    const ushortT* __restrict__ wxT,  // [NG][ND]    bf16
    const float* __restrict__ bias,
    float* __restrict__ XW,           // [NB*Tc][NG] f32
    int t0, int Tc, int tcsh)
{
    __shared__ ushortT As[128 * 32];
    __shared__ ushortT Bs[128 * 32];

    const int tid  = threadIdx.x;
    const int lane = tid & 63;
    const int wv   = tid >> 6;
    const int wr   = wv >> 1, wc = wv & 1;
    const int n0   = blockIdx.x * 128;
    const int m0   = blockIdx.y * 128;

    const int c1 = tid, c2 = tid + 256;
    const int rm1 = m0 + (c1 >> 2), rm2 = m0 + (c2 >> 2);
    const int xr1 = ((rm1 >> tcsh) * NT) + t0 + (rm1 & (Tc - 1));
    const int xr2 = ((rm2 >> tcsh) * NT) + t0 + (rm2 & (Tc - 1));
    const ushortT* ap1 = xb + (size_t)xr1 * ND + (c1 & 3) * 8;
    const ushortT* ap2 = xb + (size_t)xr2 * ND + (c2 & 3) * 8;
    const ushortT* bp1 = wxT + (size_t)(n0 + (c1 >> 2)) * ND + (c1 & 3) * 8;
    const ushortT* bp2 = wxT + (size_t)(n0 + (c2 >> 2)) * ND + (c2 & 3) * 8;

    f32x4 acc[4][4];
    #pragma unroll
    for (int m = 0; m < 4; ++m)
        #pragma unroll
        for (int n = 0; n < 4; ++n) acc[m][n] = (f32x4){0.f, 0.f, 0.f, 0.f};

    const int arow_base = (wr * 64 + (lane & 15)) * 32 + (lane >> 4) * 8;
    const int brow_base = (wc * 64 + (lane & 15)) * 32 + (lane >> 4) * 8;

    for (int k0 = 0; k0 < ND; k0 += 32) {
        short8 va1 = *(const short8*)(ap1 + k0);
        short8 va2 = *(const short8*)(ap2 + k0);
        short8 vb1 = *(const short8*)(bp1 + k0);
        short8 vb2 = *(const short8*)(bp2 + k0);
        __syncthreads();
        *(short8*)&As[c1 * 8] = va1;
        *(short8*)&As[c2 * 8] = va2;
        *(short8*)&Bs[c1 * 8] = vb1;
        *(short8*)&Bs[c2 * 8] = vb2;
        __syncthreads();
        short8 af[4], bf[4];
        #pragma unroll
        for (int m = 0; m < 4; ++m)
            af[m] = *(const short8*)&As[arow_base + m * 16 * 32];
        #pragma unroll
        for (int n = 0; n < 4; ++n)
            bf[n] = *(const short8*)&Bs[brow_base + n * 16 * 32];
        #pragma unroll
        for (int m = 0; m < 4; ++m)
            #pragma unroll
            for (int n = 0; n < 4; ++n)
                acc[m][n] = __builtin_amdgcn_mfma_f32_16x16x32_bf16(
                    af[m], bf[n], acc[m][n], 0, 0, 0);
    }

    #pragma unroll
    for (int n = 0; n < 4; ++n) {
        int col = n0 + wc * 64 + n * 16 + (lane & 15);
        float bs = bias[col];
        #pragma unroll
        for (int m = 0; m < 4; ++m) {
            #pragma unroll
            for (int r = 0; r < 4; ++r) {
                int row = m0 + wr * 64 + m * 16 + (lane >> 4) * 4 + r;
                XW[(size_t)row * NG + col] = acc[m][n][r] + bs;
            }
        }
    }
}

// ---------------------------------------------------------------------------
// Grid barrier: monotonic counter, release/acquire at agent scope.
// All NBLK blocks guaranteed co-resident (grid=64 <= 256 CUs, 1 blk/CU max res).
// ---------------------------------------------------------------------------
__device__ __forceinline__ void grid_barrier(unsigned* cnt, unsigned tgt) {
    __syncthreads();   // drains this block's stores to L2 (vmcnt 0)
    if (threadIdx.x == 0) {
        // release: wb L2 (covers whole block's stores) then signal
        __hip_atomic_fetch_add(cnt, 1u, __ATOMIC_RELEASE, __HIP_MEMORY_SCOPE_AGENT);
        while (__hip_atomic_load(cnt, __ATOMIC_RELAXED, __HIP_MEMORY_SCOPE_AGENT) < tgt) {}
    }
    __syncthreads();
    __threadfence();   // acquire: invalidate L1/L2 before reading other blocks' h
}

// ---------------------------------------------------------------------------
// Persistent LSTM recurrence.
// Block P owns hidden units j = P*16..P*16+15 (64 permuted Wh rows, resident
// in registers as 32 B-frags/wave). 8 waves = (mt: 2 batch halves) x (nt: 4
// unit quads). c-state in registers across all steps. h exchanged via 64KB
// global bf16 double buffer + grid barrier per step.
// ---------------------------------------------------------------------------
__global__ __launch_bounds__(512, 2) void lstm_persist(
    const float* __restrict__ XW,      // [NB*Tc][NG] f32 (this chunk)
    const ushortT* __restrict__ whpT,  // [4096][1024] permuted bf16
    ushortT* __restrict__ hbuf0,       // [32][1024] bf16 (h_s for even s)
    ushortT* __restrict__ hbuf1,       // [32][1024] bf16 (h_s for odd s; h0 here)
    const float* __restrict__ cinit,   // c at chunk start (c0 or cT)
    float* __restrict__ cT,
    float* __restrict__ out,           // [NB][NT][NH] f32
    float* __restrict__ hT,
    unsigned* __restrict__ cnt,
    int t0, int Tc)
{
    __shared__ ushortT hs[NB * NH];    // 64 KB exactly, XOR-swizzled rows

    const int tid  = threadIdx.x;
    const int lane = tid & 63;
    const int wv   = tid >> 6;
    const int mt   = wv >> 2;          // batch half
    const int nt   = wv & 3;           // unit quad
    const int P    = blockIdx.x;

    const int hi  = lane >> 4;         // 0..3
    const int lo  = lane & 15;
    const int gq  = (lane >> 2) & 3;   // gate index of own acc column
    const int ulo = lane & 3;
    const int j   = P * 16 + nt * 4 + ulo;
    const int nown = gq * NH + j;      // XW column (natural gate order)
    const int b0r  = mt * 16 + hi * 4; // first of this lane's 4 batch rows

    // resident B fragments (Wh): 32 k-slices, 128 VGPR
    short8 Bf[32];
    {
        const ushortT* bp = whpT + (size_t)(P * 64 + nt * 16 + lo) * NH + hi * 8;
        #pragma unroll
        for (int ks = 0; ks < 32; ++ks)
            Bf[ks] = *(const short8*)(bp + ks * 32);
    }

    // resident c state (4 batch rows x own j); redundant across the 4 g-lanes
    float creg[4];
    #pragma unroll
    for (int r = 0; r < 4; ++r)
        creg[r] = cinit[(size_t)(b0r + r) * NH + j];

    // LDS A-frag addressing
    const int arow = mt * 16 + lo;
    const unsigned abase = (unsigned)arow * 2048 + (unsigned)hi * 16;
    const unsigned amask = (unsigned)(arow & 7) << 4;

    const int tend = t0 + Tc;
    for (int t = t0; t < tend; ++t) {
        const ushortT* hbR = (t & 1) ? hbuf0 : hbuf1;  // h_{t-1}
        ushortT*       hbW = (t & 1) ? hbuf1 : hbuf0;  // h_t

        // stage h_{t-1} -> LDS (swizzled), 8 x 16B per thread, lane-coalesced
        #pragma unroll
        for (int u = 0; u < 8; ++u) {
            int c = tid + u * 512;                     // 16B-chunk index
            short8 v = *(const short8*)(hbR + c * 8);
            unsigned d = ((unsigned)c * 16u) ^ (((unsigned)(c >> 7) & 7u) << 4);
            *(short8*)((char*)hs + d) = v;
        }
        // prefetch this step's xW (own gate column, 4 batch rows)
        const float* xwp = XW + ((size_t)b0r * Tc + (t - t0)) * NG + nown;
        float xwv[4];
        #pragma unroll
        for (int r = 0; r < 4; ++r)
            xwv[r] = xwp[(size_t)r * Tc * NG];
        __syncthreads();

        // 32 chained MFMAs over K=1024 (2 independent chains)
        f32x4 acc0 = (f32x4){0.f,0.f,0.f,0.f}, acc1 = (f32x4){0.f,0.f,0.f,0.f};
        #pragma unroll
        for (int ks = 0; ks < 32; ks += 2) {
            unsigned a0 = (abase + (unsigned)ks * 64u) ^ amask;
            unsigned a1 = (abase + (unsigned)(ks + 1) * 64u) ^ amask;
            short8 af0 = *(const short8*)((char*)hs + a0);
            short8 af1 = *(const short8*)((char*)hs + a1);
            acc0 = __builtin_amdgcn_mfma_f32_16x16x32_bf16(af0, Bf[ks],     acc0, 0, 0, 0);
            acc1 = __builtin_amdgcn_mfma_f32_16x16x32_bf16(af1, Bf[ks + 1], acc1, 0, 0, 0);
        }

        // complete own-column gate preacts
        float gown[4];
        #pragma unroll
        for (int r = 0; r < 4; ++r) gown[r] = acc0[r] + acc1[r] + xwv[r];

        // exchange across the 4 gate lanes (bits 2-3 of lane)
        float g4v[4], g8v[4], g12v[4];
        #pragma unroll
        for (int r = 0; r < 4; ++r) {
            g4v[r]  = __shfl_xor(gown[r], 4);
            g8v[r]  = __shfl_xor(gown[r], 8);
            g12v[r] = __shfl_xor(gown[r], 12);
        }

        #pragma unroll
        for (int r = 0; r < 4; ++r) {
            // arr[k] = gate (gq^k); want gate G at arr[gq^G]
            float gi = pick4(gown[r], g4v[r], g8v[r], g12v[r], gq);
            float gf = pick4(gown[r], g4v[r], g8v[r], g12v[r], gq ^ 1);
            float gg = pick4(gown[r], g4v[r], g8v[r], g12v[r], gq ^ 2);
            float go = pick4(gown[r], g4v[r], g8v[r], g12v[r], gq ^ 3);
            float iv = 1.f / (1.f + __expf(-gi));
            float fv = 1.f / (1.f + __expf(-gf));
            float gv = tanhf(gg);
            float ov = 1.f / (1.f + __expf(-go));
            float cn = fv * creg[r] + iv * gv;
            float hn = ov * tanhf(cn);
            creg[r] = cn;
            if (gq == 0) {
                int b = b0r + r;
                out[((size_t)b * NT + t) * NH + j] = hn;
                hbW[b * NH + j] = f2bf(hn);
                if (t == NT - 1) hT[(size_t)b * NH + j] = hn;
                if (t == tend - 1) cT[(size_t)b * NH + j] = cn;
            }
        }

        if (t != tend - 1)
            grid_barrier(cnt, (unsigned)NBLK * (unsigned)(t - t0 + 1));
    }
}

// ---------------------------------------------------------------------------
extern "C" void kernel_launch(void* const* d_in, const int* in_sizes, int n_in,
                              void* d_out, int out_size, void* d_ws, size_t ws_size,
                              hipStream_t stream) {
    const float* x    = (const float*)d_in[0];
    const float* c0   = (const float*)d_in[1];
    const float* h0   = (const float*)d_in[2];
    const float* Wx   = (const float*)d_in[3];
    const float* Wh   = (const float*)d_in[4];
    const float* bias = (const float*)d_in[5];

    float* out = (float*)d_out;
    float* cT  = out + (size_t)NB * NT * NH;
    float* hT  = cT + (size_t)NB * NH;

    // ws layout: xb 32MB | wxT 8MB | whpT 8MB | hbuf0 64KB | hbuf1 64KB | cnt | xw
    ushortT* xb   = (ushortT*)d_ws;
    ushortT* wxT  = xb  + (size_t)NB * NT * ND;
    ushortT* whpT = wxT + (size_t)NG * ND;
    ushortT* hb0  = whpT + (size_t)NG * NH;
    ushortT* hb1  = hb0 + NB * NH;
    unsigned* cnt = (unsigned*)(hb1 + NB * NH);
    float*   xw   = (float*)(cnt + 64);   // keep alignment padding

    const size_t fixed = ((size_t)NB * NT * ND + (size_t)NG * ND + (size_t)NG * NH
                          + 2 * NB * NH) * sizeof(ushortT) + 256;
    int Tc = 512;
    while (Tc > 4 && fixed + (size_t)NB * Tc * NG * sizeof(float) > ws_size)
        Tc >>= 1;
    int tcsh = 31 - __builtin_clz(Tc);

    cast_bf16<<<(NB * NT * ND / 4 + 255) / 256, 256, 0, stream>>>(x, xb, NB * NT * ND / 4);
    cast_bf16<<<(NB * NH / 4 + 255) / 256, 256, 0, stream>>>(h0, hb1, NB * NH / 4);
    transpose_cast<<<dim3(64, 16), 256, 0, stream>>>(Wx, wxT, 0);
    transpose_cast<<<dim3(64, 16), 256, 0, stream>>>(Wh, whpT, 1);

    for (int t0 = 0; t0 < NT; t0 += Tc) {
        dim3 g(NG / 128, (NB * Tc) / 128);
        gemm_xw_mfma<<<g, 256, 0, stream>>>(xb, wxT, bias, xw, t0, Tc, tcsh);
        hipMemsetAsync(cnt, 0, sizeof(unsigned), stream);
        lstm_persist<<<NBLK, 512, 0, stream>>>(
            xw, whpT, hb0, hb1,
            (t0 == 0) ? c0 : (const float*)cT,
            cT, out, hT, cnt, t0, Tc);
    }
}

// Round 5
// 2806.919 us; speedup vs baseline: 2.9847x; 2.9847x over previous
//
#include <hip/hip_runtime.h>
#include <cstddef>

#define NB 32
#define NT 512
#define ND 1024
#define NH 1024
#define NG 4096   // 4*NH
#define NGRP 8    // batch groups (4 rows each)
#define GBLK 32   // blocks per group
#define GRID 256  // = NGRP*GBLK = #CUs; 1 block/CU guaranteed (VGPR>128)

typedef unsigned short ushortT;
typedef __attribute__((ext_vector_type(8))) short short8;   // 8 bf16 = 4 VGPR
typedef __attribute__((ext_vector_type(4))) float f32x4;

__device__ __forceinline__ ushortT f2bf(float f) {
    union { float f; unsigned u; } v; v.f = f;
    unsigned r = v.u + 0x7FFFu + ((v.u >> 16) & 1u);   // RNE
    return (ushortT)(r >> 16);
}

__device__ __forceinline__ float pick4(float a0, float a1, float a2, float a3, int s) {
    float lo = (s & 1) ? a1 : a0;
    float hi = (s & 1) ? a3 : a2;
    return (s & 2) ? hi : lo;
}

// ---------------------------------------------------------------------------
// cast float -> bf16, 4 elems/thread
// ---------------------------------------------------------------------------
__global__ __launch_bounds__(256) void cast_bf16(const float* __restrict__ src,
                                                 ushortT* __restrict__ dst, int n4)
{
    int i = blockIdx.x * 256 + threadIdx.x;
    if (i < n4) {
        float4 v = ((const float4*)src)[i];
        ushort4 o;
        o.x = f2bf(v.x); o.y = f2bf(v.y); o.z = f2bf(v.z); o.w = f2bf(v.w);
        ((ushort4*)dst)[i] = o;
    }
}

// ---------------------------------------------------------------------------
// transpose + cast: src f32 [1024][4096] -> dst bf16 [4096][1024]
// permute=1 remaps dst row n=(g*1024+j) -> (j>>2)*16 + g*4 + (j&3)
// ---------------------------------------------------------------------------
__global__ __launch_bounds__(256) void transpose_cast(
    const float* __restrict__ src, ushortT* __restrict__ dst, int permute)
{
    __shared__ ushortT tile[64][66];
    const int c0 = blockIdx.x * 64, r0 = blockIdx.y * 64;
    const int cc = threadIdx.x & 63, rq = threadIdx.x >> 6;
    #pragma unroll
    for (int ps = 0; ps < 16; ++ps) {
        int r = ps * 4 + rq;
        tile[cc][r] = f2bf(src[(size_t)(r0 + r) * NG + c0 + cc]);
    }
    __syncthreads();
    #pragma unroll
    for (int ps = 0; ps < 16; ++ps) {
        int cl = ps * 4 + rq;
        int n  = c0 + cl;
        int drow = permute ? ((((n & 1023) >> 2) << 4) | ((n >> 10) << 2) | (n & 3))
                           : n;
        dst[(size_t)drow * 1024 + r0 + cc] = tile[cl][cc];
    }
}

// ---------------------------------------------------------------------------
// xW GEMM, bf16 MFMA (unchanged)
// ---------------------------------------------------------------------------
__global__ __launch_bounds__(256) void gemm_xw_mfma(
    const ushortT* __restrict__ xb,   // [NB*NT][ND] bf16
    const ushortT* __restrict__ wxT,  // [NG][ND]    bf16
    const float* __restrict__ bias,
    float* __restrict__ XW,           // [NB*Tc][NG] f32
    int t0, int Tc, int tcsh)
{
    __shared__ ushortT As[128 * 32];
    __shared__ ushortT Bs[128 * 32];

    const int tid  = threadIdx.x;
    const int lane = tid & 63;
    const int wv   = tid >> 6;
    const int wr   = wv >> 1, wc = wv & 1;
    const int n0   = blockIdx.x * 128;
    const int m0   = blockIdx.y * 128;

    const int c1 = tid, c2 = tid + 256;
    const int rm1 = m0 + (c1 >> 2), rm2 = m0 + (c2 >> 2);
    const int xr1 = ((rm1 >> tcsh) * NT) + t0 + (rm1 & (Tc - 1));
    const int xr2 = ((rm2 >> tcsh) * NT) + t0 + (rm2 & (Tc - 1));
    const ushortT* ap1 = xb + (size_t)xr1 * ND + (c1 & 3) * 8;
    const ushortT* ap2 = xb + (size_t)xr2 * ND + (c2 & 3) * 8;
    const ushortT* bp1 = wxT + (size_t)(n0 + (c1 >> 2)) * ND + (c1 & 3) * 8;
    const ushortT* bp2 = wxT + (size_t)(n0 + (c2 >> 2)) * ND + (c2 & 3) * 8;

    f32x4 acc[4][4];
    #pragma unroll
    for (int m = 0; m < 4; ++m)
        #pragma unroll
        for (int n = 0; n < 4; ++n) acc[m][n] = (f32x4){0.f, 0.f, 0.f, 0.f};

    const int arow_base = (wr * 64 + (lane & 15)) * 32 + (lane >> 4) * 8;
    const int brow_base = (wc * 64 + (lane & 15)) * 32 + (lane >> 4) * 8;

    for (int k0 = 0; k0 < ND; k0 += 32) {
        short8 va1 = *(const short8*)(ap1 + k0);
        short8 va2 = *(const short8*)(ap2 + k0);
        short8 vb1 = *(const short8*)(bp1 + k0);
        short8 vb2 = *(const short8*)(bp2 + k0);
        __syncthreads();
        *(short8*)&As[c1 * 8] = va1;
        *(short8*)&As[c2 * 8] = va2;
        *(short8*)&Bs[c1 * 8] = vb1;
        *(short8*)&Bs[c2 * 8] = vb2;
        __syncthreads();
        short8 af[4], bf[4];
        #pragma unroll
        for (int m = 0; m < 4; ++m)
            af[m] = *(const short8*)&As[arow_base + m * 16 * 32];
        #pragma unroll
        for (int n = 0; n < 4; ++n)
            bf[n] = *(const short8*)&Bs[brow_base + n * 16 * 32];
        #pragma unroll
        for (int m = 0; m < 4; ++m)
            #pragma unroll
            for (int n = 0; n < 4; ++n)
                acc[m][n] = __builtin_amdgcn_mfma_f32_16x16x32_bf16(
                    af[m], bf[n], acc[m][n], 0, 0, 0);
    }

    #pragma unroll
    for (int n = 0; n < 4; ++n) {
        int col = n0 + wc * 64 + n * 16 + (lane & 15);
        float bs = bias[col];
        #pragma unroll
        for (int m = 0; m < 4; ++m) {
            #pragma unroll
            for (int r = 0; r < 4; ++r) {
                int row = m0 + wr * 64 + m * 16 + (lane >> 4) * 4 + r;
                XW[(size_t)row * NG + col] = acc[m][n][r] + bs;
            }
        }
    }
}

// ---------------------------------------------------------------------------
// Persistent LSTM recurrence, batch-partitioned groups.
// Group g (blockIdx&7) owns batch rows 4g..4g+3. Slot s (blockIdx>>3) owns
// hidden units 32s..32s+32 (8 waves x 4 units). Wh register-resident
// (128 VGPR/wave), c-state register-resident. h exchanged via 8KB/group
// global bf16 double buffer using RELAXED AGENT atomics (no wbl2/L2-inv) +
// per-group 32-arrival flag barrier (monotonic per step, zeroed per launch).
// ---------------------------------------------------------------------------
__global__ __launch_bounds__(512, 2) void lstm_persist(
    const float* __restrict__ XW,      // [NB*Tc][NG] f32 (this chunk)
    const ushortT* __restrict__ whpT,  // [4096][1024] permuted bf16
    unsigned* __restrict__ hb0,        // [32][512] dwords (2xbf16), parity 0
    unsigned* __restrict__ hb1,        // parity 1 (h0 lives here)
    const float* __restrict__ cinit,
    float* __restrict__ cT,
    float* __restrict__ out,           // [NB][NT][NH] f32
    float* __restrict__ hT,
    unsigned* __restrict__ flags,      // [8][512], zeroed per launch
    int t0, int Tc)
{
    __shared__ ushortT hs[16 * 1024];  // 32 KB; rows 4..15 stay zero

    const int tid  = threadIdx.x;
    const int lane = tid & 63;
    const int wv   = tid >> 6;          // 0..7
    const int g    = blockIdx.x & 7;
    const int s    = blockIdx.x >> 3;   // 0..31
    const int p    = s * 8 + wv;        // 4-unit block, 0..255

    const int lo = lane & 15;
    const int hi = lane >> 4;
    const int gq = lo >> 2;             // gate of own C column
    const int ju = p * 4 + (lo & 3);    // hidden unit of own C column

    // Wh register residency: wave's 16 gate-cols x K=1024 (128 VGPR)
    short8 Bf[32];
    {
        const ushortT* bp = whpT + (size_t)(p * 16 + lo) * NH + hi * 8;
        #pragma unroll
        for (int ks = 0; ks < 32; ++ks)
            Bf[ks] = *(const short8*)(bp + ks * 32);
    }

    // zero LDS rows 4..15 (dwords 2048..8191)
    for (int d = tid; d < 6144; d += 512)
        ((unsigned*)hs)[2048 + d] = 0u;

    // c-state registers (rows 4g..4g+3 x own unit), valid in hi==0 lanes
    float creg[4];
    #pragma unroll
    for (int r = 0; r < 4; ++r)
        creg[r] = (hi == 0) ? cinit[(size_t)(g * 4 + r) * NH + ju] : 0.f;

    const unsigned abase = (unsigned)lo * 2048u + (unsigned)hi * 16u;
    const unsigned amask = (unsigned)(lo & 7) << 4;
    unsigned* const fl = flags + g * 512;

    const int tend = t0 + Tc;
    for (int t = t0; t < tend; ++t) {
        const int trel = t - t0;
        const unsigned* hR = ((t & 1) ? hb0 : hb1) + g * 2048;  // h_{t-1}
        unsigned*       hW = ((t & 1) ? hb1 : hb0) + g * 2048;  // h_t

        // stage h_{t-1} (8 KB) -> LDS rows 0..3 (swizzled), 4 dwords/thread
        #pragma unroll
        for (int u = 0; u < 4; ++u) {
            int d = tid + u * 512;                 // 0..2047
            unsigned v = __hip_atomic_load(hR + d, __ATOMIC_RELAXED,
                                           __HIP_MEMORY_SCOPE_AGENT);
            unsigned byte = ((unsigned)d * 4u) ^ (((unsigned)(d >> 9) & 7u) << 4);
            *(unsigned*)((char*)hs + byte) = v;
        }
        // prefetch this step's xW (own column, 4 batch rows) while staging lands
        float xwv[4] = {0.f, 0.f, 0.f, 0.f};
        if (hi == 0) {
            const float* xp = XW + ((size_t)(g * 4) * Tc + trel) * NG + gq * NH + ju;
            #pragma unroll
            for (int r = 0; r < 4; ++r)
                xwv[r] = xp[(size_t)r * Tc * NG];
        }
        __syncthreads();

        // K=1024: 32 chained MFMAs (2 independent chains)
        f32x4 acc0 = (f32x4){0.f,0.f,0.f,0.f}, acc1 = (f32x4){0.f,0.f,0.f,0.f};
        #pragma unroll
        for (int ks = 0; ks < 32; ks += 2) {
            short8 a0 = *(const short8*)((char*)hs + ((abase + (unsigned)ks * 64u) ^ amask));
            short8 a1 = *(const short8*)((char*)hs + ((abase + (unsigned)(ks + 1) * 64u) ^ amask));
            acc0 = __builtin_amdgcn_mfma_f32_16x16x32_bf16(a0, Bf[ks],     acc0, 0, 0, 0);
            acc1 = __builtin_amdgcn_mfma_f32_16x16x32_bf16(a1, Bf[ks + 1], acc1, 0, 0, 0);
        }

        float gown[4];
        #pragma unroll
        for (int r = 0; r < 4; ++r) gown[r] = acc0[r] + acc1[r] + xwv[r];

        // gate exchange across lane bits 2-3 (stays within hi group)
        float g4v[4], g8v[4], g12v[4];
        #pragma unroll
        for (int r = 0; r < 4; ++r) {
            g4v[r]  = __shfl_xor(gown[r], 4);
            g8v[r]  = __shfl_xor(gown[r], 8);
            g12v[r] = __shfl_xor(gown[r], 12);
        }

        #pragma unroll
        for (int r = 0; r < 4; ++r) {
            float gi = pick4(gown[r], g4v[r], g8v[r], g12v[r], gq);
            float gf = pick4(gown[r], g4v[r], g8v[r], g12v[r], gq ^ 1);
            float gg = pick4(gown[r], g4v[r], g8v[r], g12v[r], gq ^ 2);
            float go = pick4(gown[r], g4v[r], g8v[r], g12v[r], gq ^ 3);
            float iv = 1.f / (1.f + __expf(-gi));
            float fv = 1.f / (1.f + __expf(-gf));
            float gv = tanhf(gg);
            float ov = 1.f / (1.f + __expf(-go));
            float cn = fv * creg[r] + iv * gv;
            float hn = ov * tanhf(cn);
            creg[r] = cn;

            float ph = __shfl_xor(hn, 1);   // partner unit (all lanes execute)
            if (hi == 0 && gq == 0) {
                const int b = g * 4 + r;
                if ((lo & 1) == 0) {        // lanes 0,2: pack units (ju, ju+1)
                    unsigned pair = (unsigned)f2bf(hn) | ((unsigned)f2bf(ph) << 16);
                    __hip_atomic_store(&hW[r * 512 + (ju >> 1)], pair,
                                       __ATOMIC_RELAXED, __HIP_MEMORY_SCOPE_AGENT);
                    *(float2*)&out[((size_t)b * NT + t) * NH + ju] = make_float2(hn, ph);
                }
                if (t == NT - 1)   hT[(size_t)b * NH + ju] = hn;
                if (t == tend - 1) cT[(size_t)b * NH + ju] = cn;
            }
        }

        if (t != tend - 1) {
            __syncthreads();   // drains all waves' h stores (vmcnt0 before barrier)
            if (tid == 0) {
                __hip_atomic_fetch_add(&fl[trel], 1u, __ATOMIC_RELAXED,
                                       __HIP_MEMORY_SCOPE_AGENT);
                int it = 0;
                while (__hip_atomic_load(&fl[trel], __ATOMIC_RELAXED,
                                         __HIP_MEMORY_SCOPE_AGENT) < (unsigned)GBLK
                       && ++it < 131072) {}
            }
            __syncthreads();   // whole block gated for next step
        }
    }
}

// ---------------------------------------------------------------------------
extern "C" void kernel_launch(void* const* d_in, const int* in_sizes, int n_in,
                              void* d_out, int out_size, void* d_ws, size_t ws_size,
                              hipStream_t stream) {
    const float* x    = (const float*)d_in[0];
    const float* c0   = (const float*)d_in[1];
    const float* h0   = (const float*)d_in[2];
    const float* Wx   = (const float*)d_in[3];
    const float* Wh   = (const float*)d_in[4];
    const float* bias = (const float*)d_in[5];

    float* out = (float*)d_out;
    float* cT  = out + (size_t)NB * NT * NH;
    float* hT  = cT + (size_t)NB * NH;

    // ws: xb 32MB | wxT 8MB | whpT 8MB | hb0 64KB | hb1 64KB | flags 16KB | xw
    ushortT* xb   = (ushortT*)d_ws;
    ushortT* wxT  = xb  + (size_t)NB * NT * ND;
    ushortT* whpT = wxT + (size_t)NG * ND;
    unsigned* hb0 = (unsigned*)(whpT + (size_t)NG * NH);
    unsigned* hb1 = hb0 + NB * NH / 2;
    unsigned* flags = hb1 + NB * NH / 2;
    float*   xw   = (float*)(flags + 8 * 512);

    const size_t fixed = ((size_t)NB * NT * ND + (size_t)NG * ND + (size_t)NG * NH
                          + 2 * NB * NH) * sizeof(ushortT) + 8 * 512 * 4 + 256;
    int Tc = 512;
    while (Tc > 4 && fixed + (size_t)NB * Tc * NG * sizeof(float) > ws_size)
        Tc >>= 1;
    int tcsh = 31 - __builtin_clz(Tc);

    cast_bf16<<<(NB * NT * ND / 4 + 255) / 256, 256, 0, stream>>>(x, xb, NB * NT * ND / 4);
    cast_bf16<<<(NB * NH / 4 + 255) / 256, 256, 0, stream>>>(h0, (ushortT*)hb1, NB * NH / 4);
    transpose_cast<<<dim3(64, 16), 256, 0, stream>>>(Wx, wxT, 0);
    transpose_cast<<<dim3(64, 16), 256, 0, stream>>>(Wh, whpT, 1);

    for (int t0 = 0; t0 < NT; t0 += Tc) {
        dim3 g(NG / 128, (NB * Tc) / 128);
        gemm_xw_mfma<<<g, 256, 0, stream>>>(xb, wxT, bias, xw, t0, Tc, tcsh);
        hipMemsetAsync(flags, 0, 8 * 512 * sizeof(unsigned), stream);
        lstm_persist<<<GRID, 512, 0, stream>>>(
            xw, whpT, hb0, hb1,
            (t0 == 0) ? c0 : (const float*)cT,
            cT, out, hT, flags, t0, Tc);
    }
}

// Round 6
// 2310.246 us; speedup vs baseline: 3.6264x; 1.2150x over previous
//
#include <hip/hip_runtime.h>
#include <cstddef>

#define NB 32
#define NT 512
#define ND 1024
#define NH 1024
#define NG 4096   // 4*NH
#define GRID 256  // 2 groups x 128 blocks

typedef unsigned short ushortT;
typedef __attribute__((ext_vector_type(8))) short short8;   // 8 bf16 = 4 VGPR
typedef __attribute__((ext_vector_type(4))) float f32x4;
typedef __attribute__((ext_vector_type(4))) unsigned uint4v;

__device__ __forceinline__ ushortT f2bf(float f) {
    union { float f; unsigned u; } v; v.f = f;
    unsigned r = v.u + 0x7FFFu + ((v.u >> 16) & 1u);   // RNE
    return (ushortT)(r >> 16);
}

__device__ __forceinline__ float pick4(float a0, float a1, float a2, float a3, int s) {
    float lo = (s & 1) ? a1 : a0;
    float hi = (s & 1) ? a3 : a2;
    return (s & 2) ? hi : lo;
}

__device__ __forceinline__ float fsigmoid(float x) {
    return __builtin_amdgcn_rcpf(1.f + __expf(-x));
}
__device__ __forceinline__ float ftanh(float x) {
    float xc = fminf(fmaxf(x, -15.f), 15.f);
    float e  = __expf(-2.f * xc);                 // in [9e-14, 1.1e13], finite
    return (1.f - e) * __builtin_amdgcn_rcpf(1.f + e);
}

// ---------------------------------------------------------------------------
// cast float -> bf16, 4 elems/thread
// ---------------------------------------------------------------------------
__global__ __launch_bounds__(256) void cast_bf16(const float* __restrict__ src,
                                                 ushortT* __restrict__ dst, int n4)
{
    int i = blockIdx.x * 256 + threadIdx.x;
    if (i < n4) {
        float4 v = ((const float4*)src)[i];
        ushort4 o;
        o.x = f2bf(v.x); o.y = f2bf(v.y); o.z = f2bf(v.z); o.w = f2bf(v.w);
        ((ushort4*)dst)[i] = o;
    }
}

// ---------------------------------------------------------------------------
// transpose + cast: src f32 [1024][4096] -> dst bf16 [4096][1024]
// permute=1 remaps dst row n=(g*1024+j) -> (j>>2)*16 + g*4 + (j&3)
// ---------------------------------------------------------------------------
__global__ __launch_bounds__(256) void transpose_cast(
    const float* __restrict__ src, ushortT* __restrict__ dst, int permute)
{
    __shared__ ushortT tile[64][66];
    const int c0 = blockIdx.x * 64, r0 = blockIdx.y * 64;
    const int cc = threadIdx.x & 63, rq = threadIdx.x >> 6;
    #pragma unroll
    for (int ps = 0; ps < 16; ++ps) {
        int r = ps * 4 + rq;
        tile[cc][r] = f2bf(src[(size_t)(r0 + r) * NG + c0 + cc]);
    }
    __syncthreads();
    #pragma unroll
    for (int ps = 0; ps < 16; ++ps) {
        int cl = ps * 4 + rq;
        int n  = c0 + cl;
        int drow = permute ? ((((n & 1023) >> 2) << 4) | ((n >> 10) << 2) | (n & 3))
                           : n;
        dst[(size_t)drow * 1024 + r0 + cc] = tile[cl][cc];
    }
}

// ---------------------------------------------------------------------------
// xW GEMM, bf16 MFMA. Epilogue writes PERMUTED layout:
//   xwp[(trel*NB + b)][perm(n)]  where perm(n) = ((n&1023)>>2)*16+((n>>10)<<2)+(n&3)
// ---------------------------------------------------------------------------
__global__ __launch_bounds__(256) void gemm_xw_mfma(
    const ushortT* __restrict__ xb,   // [NB*NT][ND] bf16
    const ushortT* __restrict__ wxT,  // [NG][ND]    bf16
    const float* __restrict__ bias,
    float* __restrict__ XWP,          // [Tc*NB][NG] f32, permuted cols
    int t0, int Tc, int tcsh)
{
    __shared__ ushortT As[128 * 32];
    __shared__ ushortT Bs[128 * 32];

    const int tid  = threadIdx.x;
    const int lane = tid & 63;
    const int wv   = tid >> 6;
    const int wr   = wv >> 1, wc = wv & 1;
    const int n0   = blockIdx.x * 128;
    const int m0   = blockIdx.y * 128;

    const int c1 = tid, c2 = tid + 256;
    const int rm1 = m0 + (c1 >> 2), rm2 = m0 + (c2 >> 2);
    const int xr1 = ((rm1 >> tcsh) * NT) + t0 + (rm1 & (Tc - 1));
    const int xr2 = ((rm2 >> tcsh) * NT) + t0 + (rm2 & (Tc - 1));
    const ushortT* ap1 = xb + (size_t)xr1 * ND + (c1 & 3) * 8;
    const ushortT* ap2 = xb + (size_t)xr2 * ND + (c2 & 3) * 8;
    const ushortT* bp1 = wxT + (size_t)(n0 + (c1 >> 2)) * ND + (c1 & 3) * 8;
    const ushortT* bp2 = wxT + (size_t)(n0 + (c2 >> 2)) * ND + (c2 & 3) * 8;

    f32x4 acc[4][4];
    #pragma unroll
    for (int m = 0; m < 4; ++m)
        #pragma unroll
        for (int n = 0; n < 4; ++n) acc[m][n] = (f32x4){0.f, 0.f, 0.f, 0.f};

    const int arow_base = (wr * 64 + (lane & 15)) * 32 + (lane >> 4) * 8;
    const int brow_base = (wc * 64 + (lane & 15)) * 32 + (lane >> 4) * 8;

    for (int k0 = 0; k0 < ND; k0 += 32) {
        short8 va1 = *(const short8*)(ap1 + k0);
        short8 va2 = *(const short8*)(ap2 + k0);
        short8 vb1 = *(const short8*)(bp1 + k0);
        short8 vb2 = *(const short8*)(bp2 + k0);
        __syncthreads();
        *(short8*)&As[c1 * 8] = va1;
        *(short8*)&As[c2 * 8] = va2;
        *(short8*)&Bs[c1 * 8] = vb1;
        *(short8*)&Bs[c2 * 8] = vb2;
        __syncthreads();
        short8 af[4], bf[4];
        #pragma unroll
        for (int m = 0; m < 4; ++m)
            af[m] = *(const short8*)&As[arow_base + m * 16 * 32];
        #pragma unroll
        for (int n = 0; n < 4; ++n)
            bf[n] = *(const short8*)&Bs[brow_base + n * 16 * 32];
        #pragma unroll
        for (int m = 0; m < 4; ++m)
            #pragma unroll
            for (int n = 0; n < 4; ++n)
                acc[m][n] = __builtin_amdgcn_mfma_f32_16x16x32_bf16(
                    af[m], bf[n], acc[m][n], 0, 0, 0);
    }

    #pragma unroll
    for (int n = 0; n < 4; ++n) {
        int col = n0 + wc * 64 + n * 16 + (lane & 15);
        int pc  = (((col & 1023) >> 2) << 4) | ((col >> 10) << 2) | (col & 3);
        float bs = bias[col];
        #pragma unroll
        for (int m = 0; m < 4; ++m) {
            #pragma unroll
            for (int r = 0; r < 4; ++r) {
                int rm = m0 + wr * 64 + m * 16 + (lane >> 4) * 4 + r;
                int b  = rm >> tcsh, tr = rm & (Tc - 1);
                XWP[((size_t)tr * NB + b) * NG + pc] = acc[m][n][r] + bs;
            }
        }
    }
}

// ---------------------------------------------------------------------------
// Persistent LSTM recurrence, 2 groups x 16 batch rows.
// grp = blk&1 owns rows grp*16..+16; s = blk>>1 owns units [8s, 8s+8)
// (= 32 permuted gate-cols [32s, 32s+32)). 8 waves = (ct: 2 col-tiles) x
// (ksp: 4 K-splits of 256). Wh B-frags register-resident (32 VGPR/wave).
// MFMA M=16 -> all 16 rows real. K-split partials reduced via LDS.
// h exchange: relaxed AGENT atomics + per-group 4x32-arrival flag barrier.
// ---------------------------------------------------------------------------
__global__ __launch_bounds__(512) void lstm_persist(
    const float* __restrict__ XWP,     // [Tc*NB][NG] f32, permuted cols
    const ushortT* __restrict__ whpT,  // [4096][1024] permuted bf16
    unsigned* __restrict__ hb0,        // [32][512] dwords (2xbf16), parity 0
    unsigned* __restrict__ hb1,        // parity 1 (h0 here)
    const float* __restrict__ cinit,
    float* __restrict__ cT,
    float* __restrict__ out,           // [NB][NT][NH] f32
    float* __restrict__ hT,
    unsigned* __restrict__ flags,      // [2][4][512], zeroed per launch
    int t0, int Tc)
{
    __shared__ ushortT hs[16 * 1024];      // 32 KB: A tile [16 rows][1024 k]
    __shared__ float  red[8 * 16 * 17];    // 8.5 KB: K-split C partials

    const int tid  = threadIdx.x;
    const int lane = tid & 63;
    const int wv   = tid >> 6;          // 0..7
    const int grp  = blockIdx.x & 1;
    const int s    = blockIdx.x >> 1;   // 0..127

    // MFMA-phase roles
    const int ksp = wv >> 1;            // K-split 0..3 (K range ksp*256)
    const int ct  = wv & 1;             // col-tile 0..1
    const int lo  = lane & 15;
    const int hi  = lane >> 4;

    // reduction/activation roles
    const int rrow  = tid >> 5;         // 0..15 batch row (within group)
    const int col32 = tid & 31;         // perm col within block
    const int rct   = col32 >> 4, rc16 = col32 & 15;
    const int gq    = (col32 >> 2) & 3; // own gate
    const int uu    = (col32 >> 4) * 4 + (col32 & 3);   // unit 0..7
    const int j     = s * 8 + uu;
    const int brow  = grp * 16 + rrow;  // global batch row

    // Wh register residency: 8 B-frags (32 VGPR)
    short8 Bf[8];
    {
        const ushortT* bp = whpT + (size_t)(s * 32 + ct * 16 + lo) * NH
                                 + ksp * 256 + hi * 8;
        #pragma unroll
        for (int ks = 0; ks < 8; ++ks)
            Bf[ks] = *(const short8*)(bp + ks * 32);
    }

    // c-state: one value per thread (4x redundant across gate lanes)
    float creg = cinit[(size_t)brow * NH + j];

    unsigned* const fl = flags + grp * 4 * 512;
    const int sub = s & 3;

    const int tend = t0 + Tc;
    for (int t = t0; t < tend; ++t) {
        const int trel = t - t0;
        const unsigned* hR = ((t & 1) ? hb0 : hb1) + grp * 8192;  // h_{t-1}, 16x512 dw
        unsigned*       hW = ((t & 1) ? hb1 : hb0) + grp * 8192;  // h_t

        // stage h_{t-1} (32 KB) -> LDS, swizzled; 4 x 16B chunks per thread
        #pragma unroll
        for (int u = 0; u < 4; ++u) {
            int d   = tid + u * 512;            // 16B-chunk 0..2047
            int row = d >> 7;
            int c16 = d & 127;
            const unsigned* sp = hR + row * 512 + c16 * 4;
            unsigned v0 = __hip_atomic_load(sp + 0, __ATOMIC_RELAXED, __HIP_MEMORY_SCOPE_AGENT);
            unsigned v1 = __hip_atomic_load(sp + 1, __ATOMIC_RELAXED, __HIP_MEMORY_SCOPE_AGENT);
            unsigned v2 = __hip_atomic_load(sp + 2, __ATOMIC_RELAXED, __HIP_MEMORY_SCOPE_AGENT);
            unsigned v3 = __hip_atomic_load(sp + 3, __ATOMIC_RELAXED, __HIP_MEMORY_SCOPE_AGENT);
            unsigned byte = (unsigned)row * 2048u
                          + (((unsigned)c16 * 16u) ^ (((unsigned)(row & 7)) << 4));
            *(uint4v*)((char*)hs + byte) = (uint4v){v0, v1, v2, v3};
        }
        // prefetch this step's xW (1 f32/thread, 128B-coalesced per row)
        float xv = XWP[((size_t)trel * NB + brow) * NG + s * 32 + col32];
        __syncthreads();

        // MFMA: 8 chained 16x16x32 over this wave's K-split
        f32x4 acc = (f32x4){0.f, 0.f, 0.f, 0.f};
        #pragma unroll
        for (int ks = 0; ks < 8; ++ks) {
            unsigned ab = (unsigned)lo * 2048u
                        + (((unsigned)(ksp * 512 + ks * 64 + hi * 16))
                           ^ (((unsigned)(lo & 7)) << 4));
            short8 a = *(const short8*)((char*)hs + ab);
            acc = __builtin_amdgcn_mfma_f32_16x16x32_bf16(a, Bf[ks], acc, 0, 0, 0);
        }
        #pragma unroll
        for (int r = 0; r < 4; ++r)
            red[wv * 272 + (hi * 4 + r) * 17 + lo] = acc[r];
        __syncthreads();

        // reduce 4 K-splits + xW -> own-gate preact
        float g = xv;
        #pragma unroll
        for (int kp = 0; kp < 4; ++kp)
            g += red[(kp * 2 + rct) * 272 + rrow * 17 + rc16];

        // gate exchange across lane bits 2-3 (cols +-4, +-8 same wave/row)
        float g4  = __shfl_xor(g, 4);
        float g8  = __shfl_xor(g, 8);
        float g12 = __shfl_xor(g, 12);

        float gi = pick4(g, g4, g8, g12, gq);
        float gf = pick4(g, g4, g8, g12, gq ^ 1);
        float gg = pick4(g, g4, g8, g12, gq ^ 2);
        float go = pick4(g, g4, g8, g12, gq ^ 3);

        float iv = fsigmoid(gi);
        float fv = fsigmoid(gf);
        float gv = ftanh(gg);
        float ov = fsigmoid(go);
        float cn = fv * creg + iv * gv;
        float hn = ov * ftanh(cn);
        creg = cn;

        float ph = __shfl_xor(hn, 1);   // partner unit (uu^1), all lanes
        if (gq == 0) {
            if ((col32 & 1) == 0) {     // even unit: pack pair
                unsigned pair = (unsigned)f2bf(hn) | ((unsigned)f2bf(ph) << 16);
                __hip_atomic_store(&hW[rrow * 512 + (j >> 1)], pair,
                                   __ATOMIC_RELAXED, __HIP_MEMORY_SCOPE_AGENT);
                *(float2*)&out[((size_t)brow * NT + t) * NH + j] = make_float2(hn, ph);
            }
            if (t == NT - 1)   hT[(size_t)brow * NH + j] = hn;
            if (t == tend - 1) cT[(size_t)brow * NH + j] = cn;
        }

        if (t != tend - 1) {
            __syncthreads();   // drains h stores (vmcnt0 before s_barrier)
            if (tid == 0)
                __hip_atomic_fetch_add(&fl[sub * 512 + trel], 1u,
                                       __ATOMIC_RELAXED, __HIP_MEMORY_SCOPE_AGENT);
            if (tid < 4) {
                int it = 0;
                while (__hip_atomic_load(&fl[tid * 512 + trel], __ATOMIC_RELAXED,
                                         __HIP_MEMORY_SCOPE_AGENT) < 32u
                       && ++it < (1 << 18)) {}
            }
            __syncthreads();
        }
    }
}

// ---------------------------------------------------------------------------
extern "C" void kernel_launch(void* const* d_in, const int* in_sizes, int n_in,
                              void* d_out, int out_size, void* d_ws, size_t ws_size,
                              hipStream_t stream) {
    const float* x    = (const float*)d_in[0];
    const float* c0   = (const float*)d_in[1];
    const float* h0   = (const float*)d_in[2];
    const float* Wx   = (const float*)d_in[3];
    const float* Wh   = (const float*)d_in[4];
    const float* bias = (const float*)d_in[5];

    float* out = (float*)d_out;
    float* cT  = out + (size_t)NB * NT * NH;
    float* hT  = cT + (size_t)NB * NH;

    // ws: xb 32MB | wxT 8MB | whpT 8MB | hb0 64KB | hb1 64KB | flags 16KB | xwp
    ushortT* xb   = (ushortT*)d_ws;
    ushortT* wxT  = xb  + (size_t)NB * NT * ND;
    ushortT* whpT = wxT + (size_t)NG * ND;
    unsigned* hb0 = (unsigned*)(whpT + (size_t)NG * NH);
    unsigned* hb1 = hb0 + NB * NH / 2;
    unsigned* flags = hb1 + NB * NH / 2;
    float*   xwp  = (float*)(flags + 2 * 4 * 512);

    const size_t fixed = ((size_t)NB * NT * ND + (size_t)NG * ND + (size_t)NG * NH
                          + 2 * NB * NH) * sizeof(ushortT) + 2 * 4 * 512 * 4 + 256;
    int Tc = 512;
    while (Tc > 4 && fixed + (size_t)NB * Tc * NG * sizeof(float) > ws_size)
        Tc >>= 1;
    int tcsh = 31 - __builtin_clz(Tc);

    cast_bf16<<<(NB * NT * ND / 4 + 255) / 256, 256, 0, stream>>>(x, xb, NB * NT * ND / 4);
    cast_bf16<<<(NB * NH / 4 + 255) / 256, 256, 0, stream>>>(h0, (ushortT*)hb1, NB * NH / 4);
    transpose_cast<<<dim3(64, 16), 256, 0, stream>>>(Wx, wxT, 0);
    transpose_cast<<<dim3(64, 16), 256, 0, stream>>>(Wh, whpT, 1);

    for (int t0 = 0; t0 < NT; t0 += Tc) {
        dim3 g(NG / 128, (NB * Tc) / 128);
        gemm_xw_mfma<<<g, 256, 0, stream>>>(xb, wxT, bias, xwp, t0, Tc, tcsh);
        hipMemsetAsync(flags, 0, 2 * 4 * 512 * sizeof(unsigned), stream);
        lstm_persist<<<GRID, 512, 0, stream>>>(
            xwp, whpT, hb0, hb1,
            (t0 == 0) ? c0 : (const float*)cT,
            cT, out, hT, flags, t0, Tc);
    }
}

// Round 7
// 2095.688 us; speedup vs baseline: 3.9977x; 1.1024x over previous
//
#include <hip/hip_runtime.h>
#include <cstddef>

#define NB 32
#define NT 512
#define ND 1024
#define NH 1024
#define NG 4096   // 4*NH
#define GRID 256  // 2 groups x 128 blocks

typedef unsigned short ushortT;
typedef __attribute__((ext_vector_type(8))) short short8;   // 8 bf16 = 4 VGPR
typedef __attribute__((ext_vector_type(4))) float f32x4;
typedef __attribute__((ext_vector_type(4))) unsigned uint4v;

#define GLL16(g, l) __builtin_amdgcn_global_load_lds(                      \
    (const __attribute__((address_space(1))) void*)(g),                    \
    (__attribute__((address_space(3))) void*)(l), 16, 0, 0)

__device__ __forceinline__ ushortT f2bf(float f) {
    union { float f; unsigned u; } v; v.f = f;
    unsigned r = v.u + 0x7FFFu + ((v.u >> 16) & 1u);   // RNE
    return (ushortT)(r >> 16);
}
__device__ __forceinline__ float bf2f(ushortT u) {
    union { unsigned u; float f; } v; v.u = (unsigned)u << 16; return v.f;
}

__device__ __forceinline__ float pick4(float a0, float a1, float a2, float a3, int s) {
    float lo = (s & 1) ? a1 : a0;
    float hi = (s & 1) ? a3 : a2;
    return (s & 2) ? hi : lo;
}

__device__ __forceinline__ float fsigmoid(float x) {
    return __builtin_amdgcn_rcpf(1.f + __expf(-x));
}
__device__ __forceinline__ float ftanh(float x) {
    float xc = fminf(fmaxf(x, -15.f), 15.f);
    float e  = __expf(-2.f * xc);
    return (1.f - e) * __builtin_amdgcn_rcpf(1.f + e);
}

// ---------------------------------------------------------------------------
// cast float -> bf16, 4 elems/thread
// ---------------------------------------------------------------------------
__global__ __launch_bounds__(256) void cast_bf16(const float* __restrict__ src,
                                                 ushortT* __restrict__ dst, int n4)
{
    int i = blockIdx.x * 256 + threadIdx.x;
    if (i < n4) {
        float4 v = ((const float4*)src)[i];
        ushort4 o;
        o.x = f2bf(v.x); o.y = f2bf(v.y); o.z = f2bf(v.z); o.w = f2bf(v.w);
        ((ushort4*)dst)[i] = o;
    }
}

// ---------------------------------------------------------------------------
// transpose + cast: src f32 [1024][4096] -> dst bf16 [4096][1024]
// permute=1 remaps dst row n=(g*1024+j) -> (j>>2)*16 + g*4 + (j&3)
// ---------------------------------------------------------------------------
__global__ __launch_bounds__(256) void transpose_cast(
    const float* __restrict__ src, ushortT* __restrict__ dst, int permute)
{
    __shared__ ushortT tile[64][66];
    const int c0 = blockIdx.x * 64, r0 = blockIdx.y * 64;
    const int cc = threadIdx.x & 63, rq = threadIdx.x >> 6;
    #pragma unroll
    for (int ps = 0; ps < 16; ++ps) {
        int r = ps * 4 + rq;
        tile[cc][r] = f2bf(src[(size_t)(r0 + r) * NG + c0 + cc]);
    }
    __syncthreads();
    #pragma unroll
    for (int ps = 0; ps < 16; ++ps) {
        int cl = ps * 4 + rq;
        int n  = c0 + cl;
        int drow = permute ? ((((n & 1023) >> 2) << 4) | ((n >> 10) << 2) | (n & 3))
                           : n;
        dst[(size_t)drow * 1024 + r0 + cc] = tile[cl][cc];
    }
}

// ---------------------------------------------------------------------------
// xW GEMM, bf16 MFMA, global_load_lds staging (m97 pattern).
// Epilogue: bf16 + permuted cols:  xwpb[(trel*NB+b)][perm(n)]
// ---------------------------------------------------------------------------
__global__ __launch_bounds__(256) void gemm_xw_mfma(
    const ushortT* __restrict__ xb,   // [NB*NT][ND] bf16
    const ushortT* __restrict__ wxT,  // [NG][ND]    bf16
    const float* __restrict__ bias,
    ushortT* __restrict__ XWPb,       // [Tc*NB][NG] bf16, permuted cols
    int t0, int Tc, int tcsh)
{
    __shared__ ushortT As[128 * 32];
    __shared__ ushortT Bs[128 * 32];

    const int tid  = threadIdx.x;
    const int lane = tid & 63;
    const int wv   = tid >> 6;
    const int wr   = wv >> 1, wc = wv & 1;
    const int n0   = blockIdx.x * 128;
    const int m0   = blockIdx.y * 128;

    const int c1 = tid, c2 = tid + 256;
    const int rm1 = m0 + (c1 >> 2), rm2 = m0 + (c2 >> 2);
    const int xr1 = ((rm1 >> tcsh) * NT) + t0 + (rm1 & (Tc - 1));
    const int xr2 = ((rm2 >> tcsh) * NT) + t0 + (rm2 & (Tc - 1));
    const ushortT* ap1 = xb + (size_t)xr1 * ND + (c1 & 3) * 8;
    const ushortT* ap2 = xb + (size_t)xr2 * ND + (c2 & 3) * 8;
    const ushortT* bp1 = wxT + (size_t)(n0 + (c1 >> 2)) * ND + (c1 & 3) * 8;
    const ushortT* bp2 = wxT + (size_t)(n0 + (c2 >> 2)) * ND + (c2 & 3) * 8;

    f32x4 acc[4][4];
    #pragma unroll
    for (int m = 0; m < 4; ++m)
        #pragma unroll
        for (int n = 0; n < 4; ++n) acc[m][n] = (f32x4){0.f, 0.f, 0.f, 0.f};

    const int arow_base = (wr * 64 + (lane & 15)) * 32 + (lane >> 4) * 8;
    const int brow_base = (wc * 64 + (lane & 15)) * 32 + (lane >> 4) * 8;

    for (int k0 = 0; k0 < ND; k0 += 32) {
        __syncthreads();                 // previous tile's ds reads done
        GLL16(ap1 + k0, &As[c1 * 8]);
        GLL16(ap2 + k0, &As[c2 * 8]);
        GLL16(bp1 + k0, &Bs[c1 * 8]);
        GLL16(bp2 + k0, &Bs[c2 * 8]);
        __syncthreads();                 // vmcnt(0) drain: tiles landed
        short8 af[4], bf[4];
        #pragma unroll
        for (int m = 0; m < 4; ++m)
            af[m] = *(const short8*)&As[arow_base + m * 16 * 32];
        #pragma unroll
        for (int n = 0; n < 4; ++n)
            bf[n] = *(const short8*)&Bs[brow_base + n * 16 * 32];
        #pragma unroll
        for (int m = 0; m < 4; ++m)
            #pragma unroll
            for (int n = 0; n < 4; ++n)
                acc[m][n] = __builtin_amdgcn_mfma_f32_16x16x32_bf16(
                    af[m], bf[n], acc[m][n], 0, 0, 0);
    }

    #pragma unroll
    for (int n = 0; n < 4; ++n) {
        int col = n0 + wc * 64 + n * 16 + (lane & 15);
        int pc  = (((col & 1023) >> 2) << 4) | ((col >> 10) << 2) | (col & 3);
        float bs = bias[col];
        #pragma unroll
        for (int m = 0; m < 4; ++m) {
            #pragma unroll
            for (int r = 0; r < 4; ++r) {
                int rm = m0 + wr * 64 + m * 16 + (lane >> 4) * 4 + r;
                int b  = rm >> tcsh, tr = rm & (Tc - 1);
                XWPb[((size_t)tr * NB + b) * NG + pc] = f2bf(acc[m][n][r] + bs);
            }
        }
    }
}

// ---------------------------------------------------------------------------
// Persistent LSTM recurrence, 2 groups x 16 batch rows.
// grp = blk&1 (rows grp*16..+16); s = blk>>1 owns units [8s,8s+8)
// (32 permuted gate-cols [32s,32s+32)). 8 waves = 8 K-splits of 128.
// Each wave: stages its OWN 4KB h K-slice (wave-private LDS, no barrier),
// 2 independent MFMA chains of 4 (col-tiles share each A ds_read).
// Partials reduced via LDS (1 barrier), activations, h exchange via
// relaxed AGENT atomics + per-group 4x32-arrival flag barrier.
// out-stores + next-step XWP prefetch issued AFTER flag add (off chain).
// ---------------------------------------------------------------------------
__global__ __launch_bounds__(512) void lstm_persist(
    const ushortT* __restrict__ XWPb,  // [Tc*NB][NG] bf16, permuted cols
    const ushortT* __restrict__ whpT,  // [4096][1024] permuted bf16
    unsigned* __restrict__ hb0,        // [32][512] dwords (2xbf16), parity 0
    unsigned* __restrict__ hb1,        // parity 1 (h0 here)
    const float* __restrict__ cinit,
    float* __restrict__ cT,
    float* __restrict__ out,           // [NB][NT][NH] f32
    float* __restrict__ hT,
    unsigned* __restrict__ flags,      // [2][4][512], zeroed per launch
    int t0, int Tc)
{
    __shared__ ushortT hs[8 * 2048];   // 32 KB: 8 wave-private 4KB K-slices
    __shared__ float  red[16 * 272];   // 17.4 KB: K-split C partials

    const int tid  = threadIdx.x;
    const int lane = tid & 63;
    const int wv   = tid >> 6;          // K-split 0..7 (k in [wv*128, +128))
    const int grp  = blockIdx.x & 1;
    const int s    = blockIdx.x >> 1;   // 0..127

    const int lo = lane & 15;
    const int hi = lane >> 4;

    // reduction/activation roles
    const int rrow  = tid >> 5;         // 0..15 batch row (within group)
    const int col32 = tid & 31;         // perm col within block
    const int rct   = col32 >> 4, rc16 = col32 & 15;
    const int gq    = (col32 >> 2) & 3; // own gate
    const int uu    = (col32 >> 4) * 4 + (col32 & 3);   // unit 0..7
    const int j     = s * 8 + uu;
    const int brow  = grp * 16 + rrow;  // global batch row

    // Wh register residency: Bf[ct][ks], 32 VGPR
    short8 Bf[2][4];
    #pragma unroll
    for (int ct = 0; ct < 2; ++ct)
        #pragma unroll
        for (int ks = 0; ks < 4; ++ks)
            Bf[ct][ks] = *(const short8*)(whpT
                + (size_t)(s * 32 + ct * 16 + lo) * NH + wv * 128 + ks * 32 + hi * 8);

    // c-state: one value per thread (4x redundant across gate lanes)
    float creg = cinit[(size_t)brow * NH + j];

    unsigned* const fl = flags + grp * 4 * 512;
    const int sub = s & 3;

    // prefetch first step's xW (bf16)
    ushortT xvr = XWPb[((size_t)0 * NB + brow) * NG + s * 32 + col32];

    const int tend = t0 + Tc;
    for (int t = t0; t < tend; ++t) {
        const int trel = t - t0;
        const unsigned* hR = ((t & 1) ? hb0 : hb1) + grp * 8192;  // h_{t-1}
        unsigned*       hW = ((t & 1) ? hb1 : hb0) + grp * 8192;  // h_t

        // stage own K-slice (16 rows x 128 units) -> wave-private LDS slice
        #pragma unroll
        for (int u = 0; u < 4; ++u) {
            int cc  = lane + u * 64;            // 0..255: 16B chunk of slice
            int row = cc >> 4, seg = cc & 15;
            const unsigned* sp = hR + row * 512 + wv * 64 + seg * 4;
            unsigned v0 = __hip_atomic_load(sp + 0, __ATOMIC_RELAXED, __HIP_MEMORY_SCOPE_AGENT);
            unsigned v1 = __hip_atomic_load(sp + 1, __ATOMIC_RELAXED, __HIP_MEMORY_SCOPE_AGENT);
            unsigned v2 = __hip_atomic_load(sp + 2, __ATOMIC_RELAXED, __HIP_MEMORY_SCOPE_AGENT);
            unsigned v3 = __hip_atomic_load(sp + 3, __ATOMIC_RELAXED, __HIP_MEMORY_SCOPE_AGENT);
            unsigned byte = (unsigned)(wv * 4096 + row * 256)
                          + (((unsigned)seg * 16u) ^ (((unsigned)(row & 7)) << 4));
            *(uint4v*)((char*)hs + byte) = (uint4v){v0, v1, v2, v3};
        }
        float xv = bf2f(xvr);

        // MFMA: 4 A ds_reads feed 2 independent chains (col-tiles)
        f32x4 acc0 = (f32x4){0.f, 0.f, 0.f, 0.f};
        f32x4 acc1 = (f32x4){0.f, 0.f, 0.f, 0.f};
        #pragma unroll
        for (int ks = 0; ks < 4; ++ks) {
            unsigned ab = (unsigned)(wv * 4096 + lo * 256)
                        + (((unsigned)(ks * 64 + hi * 16)) ^ (((unsigned)(lo & 7)) << 4));
            short8 a = *(const short8*)((char*)hs + ab);
            acc0 = __builtin_amdgcn_mfma_f32_16x16x32_bf16(a, Bf[0][ks], acc0, 0, 0, 0);
            acc1 = __builtin_amdgcn_mfma_f32_16x16x32_bf16(a, Bf[1][ks], acc1, 0, 0, 0);
        }
        #pragma unroll
        for (int r = 0; r < 4; ++r) {
            red[(wv * 2 + 0) * 272 + (hi * 4 + r) * 17 + lo] = acc0[r];
            red[(wv * 2 + 1) * 272 + (hi * 4 + r) * 17 + lo] = acc1[r];
        }
        __syncthreads();

        // reduce 8 K-splits + xW -> own-gate preact
        float g = xv;
        #pragma unroll
        for (int w = 0; w < 8; ++w)
            g += red[(w * 2 + rct) * 272 + rrow * 17 + rc16];

        // gate exchange across lane bits 2-3
        float g4  = __shfl_xor(g, 4);
        float g8  = __shfl_xor(g, 8);
        float g12 = __shfl_xor(g, 12);

        float gi = pick4(g, g4, g8, g12, gq);
        float gf = pick4(g, g4, g8, g12, gq ^ 1);
        float gg = pick4(g, g4, g8, g12, gq ^ 2);
        float go = pick4(g, g4, g8, g12, gq ^ 3);

        float iv = fsigmoid(gi);
        float fv = fsigmoid(gf);
        float gv = ftanh(gg);
        float ov = fsigmoid(go);
        float cn = fv * creg + iv * gv;
        float hn = ov * ftanh(cn);
        creg = cn;

        float ph = __shfl_xor(hn, 1);   // partner unit (uu^1), all lanes
        const bool wlane = (gq == 0) && ((col32 & 1) == 0);
        if (wlane) {
            unsigned pair = (unsigned)f2bf(hn) | ((unsigned)f2bf(ph) << 16);
            __hip_atomic_store(&hW[rrow * 512 + (j >> 1)], pair,
                               __ATOMIC_RELAXED, __HIP_MEMORY_SCOPE_AGENT);
        }
        __syncthreads();   // drain h-exchange stores before flag

        if (t != tend - 1) {
            if (tid == 0)
                __hip_atomic_fetch_add(&fl[sub * 512 + trel], 1u,
                                       __ATOMIC_RELAXED, __HIP_MEMORY_SCOPE_AGENT);
            // off-critical-path: out store + next-step xW prefetch
            if (wlane)
                *(float2*)&out[((size_t)brow * NT + t) * NH + j] = make_float2(hn, ph);
            xvr = XWPb[((size_t)(trel + 1) * NB + brow) * NG + s * 32 + col32];
            if (tid < 4) {
                int it = 0;
                while (__hip_atomic_load(&fl[tid * 512 + trel], __ATOMIC_RELAXED,
                                         __HIP_MEMORY_SCOPE_AGENT) < 32u
                       && ++it < (1 << 18)) {}
            }
            __syncthreads();
        } else {
            if (gq == 0) {
                if ((col32 & 1) == 0)
                    *(float2*)&out[((size_t)brow * NT + t) * NH + j] = make_float2(hn, ph);
                if (t == NT - 1) hT[(size_t)brow * NH + j] = hn;
                cT[(size_t)brow * NH + j] = cn;
            }
        }
    }
}

// ---------------------------------------------------------------------------
extern "C" void kernel_launch(void* const* d_in, const int* in_sizes, int n_in,
                              void* d_out, int out_size, void* d_ws, size_t ws_size,
                              hipStream_t stream) {
    const float* x    = (const float*)d_in[0];
    const float* c0   = (const float*)d_in[1];
    const float* h0   = (const float*)d_in[2];
    const float* Wx   = (const float*)d_in[3];
    const float* Wh   = (const float*)d_in[4];
    const float* bias = (const float*)d_in[5];

    float* out = (float*)d_out;
    float* cT  = out + (size_t)NB * NT * NH;
    float* hT  = cT + (size_t)NB * NH;

    // ws: xb 32MB | wxT 8MB | whpT 8MB | hb0 64KB | hb1 64KB | flags 16KB | xwpb
    ushortT* xb   = (ushortT*)d_ws;
    ushortT* wxT  = xb  + (size_t)NB * NT * ND;
    ushortT* whpT = wxT + (size_t)NG * ND;
    unsigned* hb0 = (unsigned*)(whpT + (size_t)NG * NH);
    unsigned* hb1 = hb0 + NB * NH / 2;
    unsigned* flags = hb1 + NB * NH / 2;
    ushortT* xwpb = (ushortT*)(flags + 2 * 4 * 512);

    const size_t fixed = ((size_t)NB * NT * ND + (size_t)NG * ND + (size_t)NG * NH
                          + 2 * NB * NH) * sizeof(ushortT) + 2 * 4 * 512 * 4 + 256;
    int Tc = 512;
    while (Tc > 4 && fixed + (size_t)NB * Tc * NG * sizeof(ushortT) > ws_size)
        Tc >>= 1;
    int tcsh = 31 - __builtin_clz(Tc);

    cast_bf16<<<(NB * NT * ND / 4 + 255) / 256, 256, 0, stream>>>(x, xb, NB * NT * ND / 4);
    cast_bf16<<<(NB * NH / 4 + 255) / 256, 256, 0, stream>>>(h0, (ushortT*)hb1, NB * NH / 4);
    transpose_cast<<<dim3(64, 16), 256, 0, stream>>>(Wx, wxT, 0);
    transpose_cast<<<dim3(64, 16), 256, 0, stream>>>(Wh, whpT, 1);

    for (int t0 = 0; t0 < NT; t0 += Tc) {
        dim3 g(NG / 128, (NB * Tc) / 128);
        gemm_xw_mfma<<<g, 256, 0, stream>>>(xb, wxT, bias, xwpb, t0, Tc, tcsh);
        hipMemsetAsync(flags, 0, 2 * 4 * 512 * sizeof(unsigned), stream);
        lstm_persist<<<GRID, 512, 0, stream>>>(
            xwpb, whpT, hb0, hb1,
            (t0 == 0) ? c0 : (const float*)cT,
            cT, out, hT, flags, t0, Tc);
    }
}